// Round 1
// baseline (25263.875 us; speedup 1.0000x reference)
//
#include <hip/hip_runtime.h>
#include <hip/hip_cooperative_groups.h>

namespace cg = cooperative_groups;

typedef __bf16 bf16x8 __attribute__((ext_vector_type(8)));
typedef float f32x4 __attribute__((ext_vector_type(4)));
typedef unsigned short u16;

__device__ __forceinline__ u16 f2bf(float f) {
  union { float f; unsigned u; } x; x.f = f;
  unsigned r = (x.u + 0x7fffu + ((x.u >> 16) & 1u)) >> 16;
  return (u16)r;
}

// ---- prep: weights fp32->bf16, bias fold, zero h0 ----
__global__ void prep_kernel(const float* __restrict__ w_ih, const float* __restrict__ w_hh,
                            const float* __restrict__ b_ih, const float* __restrict__ b_hh,
                            u16* __restrict__ wih_bf, u16* __restrict__ whh_bf,
                            float* __restrict__ bias, u16* __restrict__ h_bf) {
  int i0 = blockIdx.x * blockDim.x + threadIdx.x;
  int stride = gridDim.x * blockDim.x;
  for (int i = i0; i < 4096 * 1024; i += stride) whh_bf[i] = f2bf(w_hh[i]);
  for (int i = i0; i < 4096 * 512;  i += stride) wih_bf[i] = f2bf(w_ih[i]);
  for (int i = i0; i < 64 * 1024;   i += stride) h_bf[i] = 0;
  for (int i = i0; i < 4096;        i += stride) bias[i] = b_ih[i] + b_hh[i];
}

// ---- embedding gather -> A1[t*64+b][512] bf16 ----
__global__ void gather_kernel(const int* __restrict__ sent, const float* __restrict__ emb,
                              u16* __restrict__ A1) {
  int row = blockIdx.x * 4 + (threadIdx.x >> 6);   // t*64+b, 0..32767
  int lane = threadIdx.x & 63;
  int t = row >> 6, b = row & 63;
  int idx = sent[b * 512 + t];
  const float* src = emb + (size_t)idx * 512 + lane * 8;
  u16* dst = A1 + (size_t)row * 512 + lane * 8;
  #pragma unroll
  for (int k = 0; k < 8; ++k) dst[k] = f2bf(src[k]);
}

// ---- fused LSTM recurrence (cooperative, 64 WGs x 512 thr) ----
// WG j owns h columns [j*16, j*16+16). Wave (mi,p): batch rows mi*16..+16,
// gates {2p, 2p+1}. K = 512 (x-proj from A1) + 1024 (h-proj). One grid.sync/step.
__global__ void __launch_bounds__(512, 1)
lstm_kernel(const u16* __restrict__ A1, const u16* __restrict__ wih,
            const u16* __restrict__ whh, const float* __restrict__ bias,
            u16* __restrict__ h_bf, float* __restrict__ out) {
  cg::grid_group grid = cg::this_grid();
  __shared__ float exch[2][4][16][16];   // [g|o][mi][m][n]

  const int j  = blockIdx.x;             // 0..63
  const int w  = threadIdx.x >> 6;       // 0..7
  const int mi = w & 3, p = w >> 2;
  const int l  = threadIdx.x & 63;
  const int lr = l & 15, lk = l >> 4;

  const int g0 = 2 * p, g1 = 2 * p + 1;
  const int n0 = g0 * 1024 + j * 16 + lr;   // B-fragment row (output col) gate g0
  const int n1 = g1 * 1024 + j * 16 + lr;
  const int am = mi * 16 + lr;              // A-fragment row (batch)
  const int cm = mi * 16 + lk * 4;          // C/D row base (+r)
  const int cn = j * 16 + lr;               // C/D col within 1024

  const float bias0 = bias[g0 * 1024 + j * 16 + lr];
  const float bias1 = bias[g1 * 1024 + j * 16 + lr];

  const u16* b0x = wih + (size_t)n0 * 512 + lk * 8;
  const u16* b1x = wih + (size_t)n1 * 512 + lk * 8;
  const u16* b0h = whh + (size_t)n0 * 1024 + lk * 8;
  const u16* b1h = whh + (size_t)n1 * 1024 + lk * 8;
  const u16* hrow = h_bf + (size_t)am * 1024 + lk * 8;

  float cst[4] = {0.f, 0.f, 0.f, 0.f};

  for (int t = 0; t < 512; ++t) {
    f32x4 acc0, acc1;
    #pragma unroll
    for (int r = 0; r < 4; ++r) { acc0[r] = bias0; acc1[r] = bias1; }

    // x-projection: K=512 over A1 rows for this timestep
    const u16* arow = A1 + ((size_t)(t * 64) + am) * 512 + lk * 8;
    #pragma unroll 4
    for (int kk = 0; kk < 16; ++kk) {
      bf16x8 a  = *(const bf16x8*)(arow + kk * 32);
      bf16x8 b0 = *(const bf16x8*)(b0x + kk * 32);
      bf16x8 b1 = *(const bf16x8*)(b1x + kk * 32);
      acc0 = __builtin_amdgcn_mfma_f32_16x16x32_bf16(a, b0, acc0, 0, 0, 0);
      acc1 = __builtin_amdgcn_mfma_f32_16x16x32_bf16(a, b1, acc1, 0, 0, 0);
    }
    // h-projection: K=1024
    #pragma unroll 4
    for (int kk = 0; kk < 32; ++kk) {
      bf16x8 a  = *(const bf16x8*)(hrow + kk * 32);
      bf16x8 b0 = *(const bf16x8*)(b0h + kk * 32);
      bf16x8 b1 = *(const bf16x8*)(b1h + kk * 32);
      acc0 = __builtin_amdgcn_mfma_f32_16x16x32_bf16(a, b0, acc0, 0, 0, 0);
      acc1 = __builtin_amdgcn_mfma_f32_16x16x32_bf16(a, b1, acc1, 0, 0, 0);
    }

    if (p == 1) {   // gates g (tanh) and o (sigmoid)
      #pragma unroll
      for (int r = 0; r < 4; ++r) {
        float gv = tanhf(acc0[r]);
        float ov = 1.f / (1.f + expf(-acc1[r]));
        exch[0][mi][lk * 4 + r][lr] = gv;
        exch[1][mi][lk * 4 + r][lr] = ov;
      }
    }
    __syncthreads();
    if (p == 0) {   // gates i, f + state update
      #pragma unroll
      for (int r = 0; r < 4; ++r) {
        float iv = 1.f / (1.f + expf(-acc0[r]));
        float fv = 1.f / (1.f + expf(-acc1[r]));
        float gv = exch[0][mi][lk * 4 + r][lr];
        float ov = exch[1][mi][lk * 4 + r][lr];
        float c  = fv * cst[r] + iv * gv;
        cst[r] = c;
        float h  = ov * tanhf(c);
        int m = cm + r;
        h_bf[(size_t)m * 1024 + cn] = f2bf(h);
        if (t == 511) {
          out[(size_t)m * 1024 + cn]          = h;  // output
          out[65536 + (size_t)m * 1024 + cn]  = h;  // h_n
          out[131072 + (size_t)m * 1024 + cn] = c;  // c_n
        }
      }
      __threadfence();
    }
    grid.sync();
  }
}

extern "C" void kernel_launch(void* const* d_in, const int* in_sizes, int n_in,
                              void* d_out, int out_size, void* d_ws, size_t ws_size,
                              hipStream_t stream) {
  const int*   sent = (const int*)d_in[0];
  const float* emb  = (const float*)d_in[1];
  const float* w_ih = (const float*)d_in[2];
  const float* w_hh = (const float*)d_in[3];
  const float* b_ih = (const float*)d_in[4];
  const float* b_hh = (const float*)d_in[5];
  float* out = (float*)d_out;

  char* ws = (char*)d_ws;
  u16*   whh_bf = (u16*)(ws);                       // 8 MiB
  u16*   wih_bf = (u16*)(ws + 8388608);             // 4 MiB
  float* bias   = (float*)(ws + 12582912);          // 16 KiB
  u16*   h_bf   = (u16*)(ws + 12599296);            // 128 KiB
  u16*   A1     = (u16*)(ws + 12730368);            // 32 MiB  (total ~45 MiB)

  prep_kernel<<<2048, 256, 0, stream>>>(w_ih, w_hh, b_ih, b_hh, wih_bf, whh_bf, bias, h_bf);
  gather_kernel<<<8192, 256, 0, stream>>>(sent, emb, A1);

  void* args[] = { (void*)&A1, (void*)&wih_bf, (void*)&whh_bf,
                   (void*)&bias, (void*)&h_bf, (void*)&out };
  hipLaunchCooperativeKernel((void*)lstm_kernel, dim3(64), dim3(512), args, 0, stream);
}

// Round 2
// 12009.995 us; speedup vs baseline: 2.1036x; 2.1036x over previous
//
#include <hip/hip_runtime.h>

typedef __bf16 bf16x8 __attribute__((ext_vector_type(8)));
typedef float f32x4 __attribute__((ext_vector_type(4)));
typedef unsigned short u16;

#define NWG 256
#define NSTEP 512

__device__ __forceinline__ u16 f2bf(float f) {
  union { float f; unsigned u; } x; x.f = f;
  return (u16)((x.u + 0x7fffu + ((x.u >> 16) & 1u)) >> 16);
}

// zero h buffer 0 + barrier state (runs every call -> deterministic replays)
__global__ void prep_kernel(u16* __restrict__ h0, int* __restrict__ bar) {
  int i = blockIdx.x * blockDim.x + threadIdx.x;
  if (i < 65536) h0[i] = 0;
  if (i < 32) bar[i] = 0;
}

// A1[t*64+b][512] bf16 embedding gather
__global__ void gather_kernel(const int* __restrict__ sent, const float* __restrict__ emb,
                              u16* __restrict__ A1) {
  int row = blockIdx.x * 4 + (threadIdx.x >> 6);   // t*64+b
  int lane = threadIdx.x & 63;
  int t = row >> 6, b = row & 63;
  int idx = sent[b * 512 + t];
  const float* src = emb + (size_t)idx * 512 + lane * 8;
  u16* dst = A1 + (size_t)row * 512 + lane * 8;
  #pragma unroll
  for (int k = 0; k < 8; ++k) dst[k] = f2bf(src[k]);
}

// 256 WGs x 256 thr. WG j owns h cols [j*4, j*4+4), all 4 gates packed:
// B-tile row rb = g*4+n -> weight row g*1024 + j*4 + n. Weights live in LDS.
// Wave w = batch tile (rows w*16..+15). acc[r] = gates for row lk*4+r, packed col lr.
__global__ void __launch_bounds__(256, 1)
lstm_kernel(const u16* __restrict__ A1,
            const float* __restrict__ wih, const float* __restrict__ whh,
            const float* __restrict__ bih, const float* __restrict__ bhh,
            u16* __restrict__ h3, float* __restrict__ out, int* __restrict__ bar) {
  __shared__ u16 wlds[48 * 16 * 40];   // [kk][rb][32+8 pad] u16 = 61440 B

  const int j   = blockIdx.x;
  const int tid = threadIdx.x;
  const int w   = tid >> 6;            // wave = batch tile 0..3
  const int l   = tid & 63;
  const int lr  = l & 15, lk = l >> 4;
  const int g   = lr >> 2, nn = lr & 3;

  // ---- stage weights fp32->bf16 into padded LDS (once) ----
  for (int task = tid; task < 3072; task += 256) {
    int kk = task >> 6;                 // 0..47 (K chunk of 32)
    int rem = task & 63;
    int rb = rem >> 2, q = rem & 3;     // rb = gate*4+col, q = k-subquarter
    int row = (rb >> 2) * 1024 + j * 4 + (rb & 3);
    const float* src = (kk < 16) ? (wih + (size_t)row * 512 + kk * 32 + q * 8)
                                 : (whh + (size_t)row * 1024 + (kk - 16) * 32 + q * 8);
    u16* dst = wlds + (kk * 16 + rb) * 40 + q * 8;
    #pragma unroll
    for (int e = 0; e < 8; ++e) dst[e] = f2bf(src[e]);
  }
  __syncthreads();

  const int gr = g * 1024 + j * 4 + nn;
  const float bias = bih[gr] + bhh[gr];
  const float sca = (g == 2) ? 2.f : 1.f;   // tanh-as-sigmoid scaling for gate g
  const float bd  = (g == 2) ? -1.f : 0.f;

  const int arow = w * 16 + lr;             // batch row for A fragment
  const u16* bx = wlds + lr * 40 + lk * 8;  // + kk*640 per K chunk

  float cst[4] = {0.f, 0.f, 0.f, 0.f};
  int mygen = 0;

  // preload A1 fragments for t=0 (registers survive cache invalidation)
  bf16x8 ax[16];
  {
    const u16* ap = A1 + (size_t)arow * 512 + lk * 8;
    #pragma unroll
    for (int kk = 0; kk < 16; ++kk) ax[kk] = *(const bf16x8*)(ap + kk * 32);
  }

  for (int t = 0; t < NSTEP; ++t) {
    f32x4 acc = { bias, bias, bias, bias };
    // x-projection (K=512) from prefetched regs
    #pragma unroll
    for (int kk = 0; kk < 16; ++kk) {
      bf16x8 b = *(const bf16x8*)(bx + kk * 640);
      acc = __builtin_amdgcn_mfma_f32_16x16x32_bf16(ax[kk], b, acc, 0, 0, 0);
    }
    // h-projection (K=1024): 32-deep load burst then MFMA
    const u16* hb = h3 + (size_t)(t % 3) * 65536 + (size_t)arow * 1024 + lk * 8;
    bf16x8 ah[32];
    #pragma unroll
    for (int kk = 0; kk < 32; ++kk) ah[kk] = *(const bf16x8*)(hb + kk * 32);
    #pragma unroll
    for (int kk = 0; kk < 32; ++kk) {
      bf16x8 b = *(const bf16x8*)(bx + (16 + kk) * 640);
      acc = __builtin_amdgcn_mfma_f32_16x16x32_bf16(ah[kk], b, acc, 0, 0, 0);
    }
    // prefetch A1 for t+1 (latency hides under activations + barrier)
    if (t < NSTEP - 1) {
      const u16* ap = A1 + ((size_t)(t + 1) * 64 + arow) * 512 + lk * 8;
      #pragma unroll
      for (int kk = 0; kk < 16; ++kk) ax[kk] = *(const bf16x8*)(ap + kk * 32);
    }
    // activations + state update; lanes lr<4 own (row, col=lr)
    u16* hw = h3 + (size_t)((t + 1) % 3) * 65536;
    #pragma unroll
    for (int r = 0; r < 4; ++r) {
      float xv = acc[r];
      float act = sca / (1.f + __expf(-sca * xv)) + bd;  // sigmoid or tanh
      float gg = __shfl_xor(act, 8);    // lane n <- n+8  : g~
      float ff = __shfl_xor(act, 4);    // lane n <- n+4  : f
      float oo = __shfl_xor(act, 12);   // lane n <- n+12 : o
      float cn = ff * cst[r] + act * gg;  // act = i at lanes lr<4
      cst[r] = cn;
      float tc = 2.f / (1.f + __expf(-2.f * cn)) - 1.f;
      float hv = oo * tc;
      if (lr < 4) {
        int R = w * 16 + lk * 4 + r;
        hw[(size_t)R * 1024 + j * 4 + lr] = f2bf(hv);
        if (t == NSTEP - 1) {
          out[(size_t)R * 1024 + j * 4 + lr] = hv;
          out[65536 + (size_t)R * 1024 + j * 4 + lr] = hv;
          out[131072 + (size_t)R * 1024 + j * 4 + lr] = cn;
        }
      }
    }
    // ---- lightweight 2-level grid barrier ----
    if (t < NSTEP - 1) {
      __syncthreads();                   // drains each wave's h stores into L2
      if (tid == 0) {
        __threadfence();                 // release: L2 writeback so h reaches L3
        ++mygen;
        int a = __hip_atomic_fetch_add(&bar[j & 15], 1, __ATOMIC_RELAXED, __HIP_MEMORY_SCOPE_AGENT);
        if (a == 15) {
          int rt = __hip_atomic_fetch_add(&bar[16], 1, __ATOMIC_RELAXED, __HIP_MEMORY_SCOPE_AGENT);
          if (rt == 15) {                // last WG: reset + flip generation
            #pragma unroll
            for (int q2 = 0; q2 < 17; ++q2)
              __hip_atomic_store(&bar[q2], 0, __ATOMIC_RELAXED, __HIP_MEMORY_SCOPE_AGENT);
            __hip_atomic_store(&bar[17], mygen, __ATOMIC_RELEASE, __HIP_MEMORY_SCOPE_AGENT);
          } else {
            while (__hip_atomic_load(&bar[17], __ATOMIC_RELAXED, __HIP_MEMORY_SCOPE_AGENT) < mygen)
              __builtin_amdgcn_s_sleep(1);
          }
        } else {
          while (__hip_atomic_load(&bar[17], __ATOMIC_RELAXED, __HIP_MEMORY_SCOPE_AGENT) < mygen)
            __builtin_amdgcn_s_sleep(1);
        }
        __threadfence();                 // acquire: invalidate L1/L2 for fresh h
      }
      __syncthreads();
    }
  }
}

extern "C" void kernel_launch(void* const* d_in, const int* in_sizes, int n_in,
                              void* d_out, int out_size, void* d_ws, size_t ws_size,
                              hipStream_t stream) {
  const int*   sent = (const int*)d_in[0];
  const float* emb  = (const float*)d_in[1];
  const float* w_ih = (const float*)d_in[2];
  const float* w_hh = (const float*)d_in[3];
  const float* b_ih = (const float*)d_in[4];
  const float* b_hh = (const float*)d_in[5];
  float* out = (float*)d_out;

  char* ws = (char*)d_ws;
  u16* A1 = (u16*)ws;                            // 32 MiB
  u16* h3 = (u16*)(ws + 33554432);               // 3 x 128 KiB triple-buffered h
  int* bar = (int*)(ws + 33554432 + 393216);     // barrier state (32 ints)

  prep_kernel<<<256, 256, 0, stream>>>(h3, bar);
  gather_kernel<<<8192, 256, 0, stream>>>(sent, emb, A1);

  void* args[] = { (void*)&A1, (void*)&w_ih, (void*)&w_hh,
                   (void*)&b_ih, (void*)&b_hh, (void*)&h3, (void*)&out, (void*)&bar };
  hipLaunchCooperativeKernel((void*)lstm_kernel, dim3(NWG), dim3(256), args, 0, stream);
}

// Round 5
// 5606.790 us; speedup vs baseline: 4.5059x; 2.1420x over previous
//
#include <hip/hip_runtime.h>

typedef __bf16 bf16x8 __attribute__((ext_vector_type(8)));
typedef float f32x4 __attribute__((ext_vector_type(4)));
typedef unsigned short u16;
typedef unsigned long long u64;

#define NSTEP 512
#define RELIDX 8224

#define AL(p)   __hip_atomic_load((p), __ATOMIC_RELAXED, __HIP_MEMORY_SCOPE_AGENT)
#define AS(p,v) __hip_atomic_store((p), (v), __ATOMIC_RELAXED, __HIP_MEMORY_SCOPE_AGENT)

__device__ __forceinline__ u16 f2bf(float f) {
  union { float f; unsigned u; } x; x.f = f;
  return (u16)((x.u + 0x7fffu + ((x.u >> 16) & 1u)) >> 16);
}

// zero h buffer 0 + barrier flags (runs every call -> deterministic replays)
__global__ void prep_kernel(u16* __restrict__ h0, int* __restrict__ bar) {
  int i = blockIdx.x * blockDim.x + threadIdx.x;
  if (i < 65536) h0[i] = 0;
  if (i < 8256) bar[i] = 0;
}

// A1[t*64+b][512] bf16 embedding gather
__global__ void gather_kernel(const int* __restrict__ sent, const float* __restrict__ emb,
                              u16* __restrict__ A1) {
  int row = blockIdx.x * 4 + (threadIdx.x >> 6);   // t*64+b
  int lane = threadIdx.x & 63;
  int t = row >> 6, b = row & 63;
  int idx = sent[b * 512 + t];
  const float* src = emb + (size_t)idx * 512 + lane * 8;
  u16* dst = A1 + (size_t)row * 512 + lane * 8;
  #pragma unroll
  for (int k = 0; k < 8; ++k) dst[k] = f2bf(src[k]);
}

// 256 WGs x 256 thr. WG j owns h cols [j*4,j*4+4), 4 gates packed (rb = g*4+nn = lr).
// Weights in padded LDS (r2 envelope); h exchanged via agent-scope relaxed atomics;
// padded-flag barrier, no threadfence.
__global__ void __launch_bounds__(256, 2)
lstm_kernel(const u16* __restrict__ A1,
            const float* __restrict__ wih, const float* __restrict__ whh,
            const float* __restrict__ bih, const float* __restrict__ bhh,
            u16* __restrict__ h3, float* __restrict__ out, int* __restrict__ bar) {
  __shared__ u16 wlds[48 * 16 * 36];        // 55296 B, stride-36 pad (16 distinct banks)
  __shared__ alignas(8) u16 hx[4][16][4];   // per-wave h-store packing bounce

  const int j   = blockIdx.x;
  const int tid = threadIdx.x;
  const int w   = tid >> 6;            // wave = batch tile 0..3
  const int l   = tid & 63;
  const int lr  = l & 15, lk = l >> 4;
  const int g   = lr >> 2, nn = lr & 3;
  const int wrow = g * 1024 + j * 4 + nn;

  // ---- stage ALL weights fp32->bf16 into padded LDS (once) ----
  for (int task = tid; task < 3072; task += 256) {
    int kk = task >> 6;                 // K chunk of 32 (0..47)
    int rem = task & 63;
    int rb = rem >> 2, q = rem & 3;
    int row = (rb >> 2) * 1024 + j * 4 + (rb & 3);
    const float* src = (kk < 16) ? (wih + (size_t)row * 512 + kk * 32 + q * 8)
                                 : (whh + (size_t)row * 1024 + (kk - 16) * 32 + q * 8);
    u16* dst = wlds + (kk * 16 + rb) * 36 + q * 8;
    #pragma unroll
    for (int e = 0; e < 8; ++e) dst[e] = f2bf(src[e]);
  }
  __syncthreads();

  const float bias = bih[wrow] + bhh[wrow];
  const float sca = (g == 2) ? 2.f : 1.f;   // tanh-as-sigmoid scaling
  const float bd  = (g == 2) ? -1.f : 0.f;
  const int arow = w * 16 + lr;             // batch row for A fragments
  const u16* bx = wlds + lr * 36 + lk * 8;  // + kk*576 per K chunk

  float cst[4] = {0.f, 0.f, 0.f, 0.f};

  // prefetch A1 fragments for t=0
  bf16x8 ax[16];
  {
    const u16* apre = A1 + (size_t)arow * 512 + lk * 8;
    #pragma unroll
    for (int kk = 0; kk < 16; ++kk) ax[kk] = *(const bf16x8*)(apre + kk * 32);
  }

  union AF { bf16x8 v; u64 q[2]; };

#define LD8(BUF, CH)                                                        \
  { _Pragma("unroll")                                                       \
    for (int r = 0; r < 8; ++r) {                                           \
      u64* p = (u64*)(hp + (CH) * 256 + r * 32);                            \
      BUF[r].q[0] = AL(p); BUF[r].q[1] = AL(p + 1);                         \
    } }
#define MM8(BUF, W0)                                                        \
  { _Pragma("unroll")                                                       \
    for (int r = 0; r < 8; ++r) {                                           \
      bf16x8 b = *(const bf16x8*)(bx + ((W0) + r) * 576);                   \
      acc = __builtin_amdgcn_mfma_f32_16x16x32_bf16(BUF[r].v, b, acc, 0, 0, 0); \
    } }

  #pragma unroll 1
  for (int t = 0; t < NSTEP; ++t) {
    AF ha[8], hb[8];
    const u16* hp = h3 + (size_t)(t % 3) * 65536 + (size_t)arow * 1024 + lk * 8;
    LD8(ha, 0);                          // h chunk 0 in flight
    // x-projection from prefetched ax (overlaps h-load latency)
    f32x4 acc = { bias, bias, bias, bias };
    #pragma unroll
    for (int kk = 0; kk < 16; ++kk) {
      bf16x8 b = *(const bf16x8*)(bx + kk * 576);
      acc = __builtin_amdgcn_mfma_f32_16x16x32_bf16(ax[kk], b, acc, 0, 0, 0);
    }
    // h-projection: double-buffered 8-fragment chunks (static names, no scratch)
    LD8(hb, 1); MM8(ha, 16);
    LD8(ha, 2); MM8(hb, 24);
    LD8(hb, 3); MM8(ha, 32);
    MM8(hb, 40);

    // activations + state update; lanes lr<4 own (rows lk*4+r, col lr)
    float hv4[4], cn4[4];
    #pragma unroll
    for (int r = 0; r < 4; ++r) {
      float xv = acc[r];
      float act = sca / (1.f + __expf(-sca * xv)) + bd;  // sigmoid / tanh
      float gg = __shfl_xor(act, 8);
      float ff = __shfl_xor(act, 4);
      float oo = __shfl_xor(act, 12);
      float cn = ff * cst[r] + act * gg;   // act = i at lanes lr<4
      cst[r] = cn;
      float tc = 2.f / (1.f + __expf(-2.f * cn)) - 1.f;
      hv4[r] = oo * tc;
      cn4[r] = cn;
    }

    if (t == NSTEP - 1) {
      if (lr < 4) {
        #pragma unroll
        for (int r = 0; r < 4; ++r) {
          int R = w * 16 + lk * 4 + r;
          out[(size_t)R * 1024 + j * 4 + lr]          = hv4[r];
          out[65536 + (size_t)R * 1024 + j * 4 + lr]  = hv4[r];
          out[131072 + (size_t)R * 1024 + j * 4 + lr] = cn4[r];
        }
      }
    } else {
      // pack h tile 64x4 -> one 8B agent-scope store per row
      if (lr < 4) {
        #pragma unroll
        for (int r = 0; r < 4; ++r) hx[w][lk * 4 + r][lr] = f2bf(hv4[r]);
      }
      __syncthreads();
      if (l < 16) {
        u64 pk = *(const u64*)(&hx[w][l][0]);
        u16* hw = h3 + (size_t)((t + 1) % 3) * 65536 + (size_t)(w * 16 + l) * 1024 + j * 4;
        AS((u64*)hw, pk);
      }
      // each wave drains its own h stores; syncthreads orders all before the flag
      asm volatile("s_waitcnt vmcnt(0)" ::: "memory");
      __syncthreads();
      const int t1 = t + 1;
      if (tid == 0) AS(&bar[j * 32], t1);
      // prefetch A1 for t+1; latency hides under the barrier poll
      {
        const u16* apre = A1 + ((size_t)t1 * 64 + arow) * 512 + lk * 8;
        #pragma unroll
        for (int kk = 0; kk < 16; ++kk) ax[kk] = *(const bf16x8*)(apre + kk * 32);
      }
      if (j == 0) {      // WG0: 256 threads poll 256 flags in parallel
        while (AL(&bar[tid * 32]) < t1) __builtin_amdgcn_s_sleep(1);
        __syncthreads();
        if (tid == 0) AS(&bar[RELIDX], t1);
      } else {
        if (tid == 0) {
          while (AL(&bar[RELIDX]) < t1) __builtin_amdgcn_s_sleep(1);
        }
      }
      __syncthreads();
    }
  }
#undef LD8
#undef MM8
}

extern "C" void kernel_launch(void* const* d_in, const int* in_sizes, int n_in,
                              void* d_out, int out_size, void* d_ws, size_t ws_size,
                              hipStream_t stream) {
  const int*   sent = (const int*)d_in[0];
  const float* emb  = (const float*)d_in[1];
  const float* w_ih = (const float*)d_in[2];
  const float* w_hh = (const float*)d_in[3];
  const float* b_ih = (const float*)d_in[4];
  const float* b_hh = (const float*)d_in[5];
  float* out = (float*)d_out;

  char* ws = (char*)d_ws;
  u16* A1 = (u16*)ws;                            // 32 MiB
  u16* h3 = (u16*)(ws + 33554432);               // 3 x 128 KiB triple-buffered h
  int* bar = (int*)(ws + 33554432 + 393216);     // padded flags + release line

  prep_kernel<<<256, 256, 0, stream>>>(h3, bar);
  gather_kernel<<<8192, 256, 0, stream>>>(sent, emb, A1);

  void* args[] = { (void*)&A1, (void*)&w_ih, (void*)&w_hh,
                   (void*)&b_ih, (void*)&b_hh, (void*)&h3, (void*)&out, (void*)&bar };
  hipError_t err = hipLaunchCooperativeKernel((void*)lstm_kernel, dim3(256), dim3(256),
                                              args, 0, stream);
  if (err != hipSuccess) {
    // barrier is custom (no cg grid.sync): plain launch works when all 256 WGs
    // are co-resident, which >=2 blocks/CU occupancy guarantees on a 256-CU part
    lstm_kernel<<<dim3(256), dim3(256), 0, stream>>>(A1, w_ih, w_hh, b_ih, b_hh,
                                                     h3, out, bar);
  }
}